// Round 6
// baseline (329.053 us; speedup 1.0000x reference)
//
#include <hip/hip_runtime.h>
#include <math.h>

#define BB 16384
#define DD 1024
#define RR 64
#define EE 4
#define ER 256   // EE*RR
#define LL 3

#define LDM 72   // mix-phase Tt stride

typedef __bf16 bf16x8 __attribute__((ext_vector_type(8)));
typedef float f32x4 __attribute__((ext_vector_type(4)));
typedef unsigned short us;

static __device__ inline us f2b(float f) {   // RNE f32->bf16
    union { float f; unsigned u; } c; c.f = f;
    return (us)((c.u + 0x7FFF + ((c.u >> 16) & 1)) >> 16);
}
static __device__ inline float b2f(us v) {
    union { unsigned u; float f; } c; c.u = ((unsigned)v) << 16;
    return c.f;
}
static __device__ inline float fast_tanh(float x) {
    float t = __expf(2.f * x);               // inf/0 at extremes -> +-1 exactly
    return 1.f - 2.f / (t + 1.f);
}
// async global->LDS, 16B/lane; dst is wave-uniform base, HW writes lane i at base+i*16
static __device__ __forceinline__ void ld_lds16(const us* g, us* l) {
    __builtin_amdgcn_global_load_lds((const __attribute__((address_space(1))) void*)g,
                                     (__attribute__((address_space(3))) void*)l, 16, 0, 0);
}

// generic f32 -> bf16 (4 elems/thread)
__global__ __launch_bounds__(256) void convF2B(const float* __restrict__ s, us* __restrict__ d) {
    int f = (blockIdx.x * 256 + threadIdx.x) * 4;
    float4 v = *(const float4*)&s[f];
    *(ushort4*)&d[f] = make_ushort4(f2b(v.x), f2b(v.y), f2b(v.z), f2b(v.w));
}
// V [le][d][r] f32 -> Vt [le][r][d] bf16
__global__ __launch_bounds__(256) void convV(const float* __restrict__ V, us* __restrict__ Vt) {
    const int le = blockIdx.x;
    const int d0 = blockIdx.y * 64;
    __shared__ float t[64 * 65];
    const int tid = threadIdx.x;
    const float* Vb = V + (size_t)le * DD * RR;
    #pragma unroll
    for (int p = 0; p < 4; ++p) {
        int f = tid + p * 256; int dd = f >> 4; int c = (f & 15) * 4;
        float4 v = *(const float4*)&Vb[(size_t)(d0 + dd) * RR + c];
        t[dd * 65 + c + 0] = v.x; t[dd * 65 + c + 1] = v.y;
        t[dd * 65 + c + 2] = v.z; t[dd * 65 + c + 3] = v.w;
    }
    __syncthreads();
    int r = tid >> 2, dg = (tid & 3) * 16;
    us o[16];
    #pragma unroll
    for (int k = 0; k < 16; ++k) o[k] = f2b(t[(dg + k) * 65 + r]);
    us* dst = Vt + (size_t)le * RR * DD + (size_t)r * DD + d0 + dg;
    #pragma unroll
    for (int q = 0; q < 4; ++q) *(ushort4*)&dst[q * 4] = *(ushort4*)&o[q * 4];
}

// Whole layer fused; block = 32 b-rows, 512 thr (8 waves), 2 blocks/CU (LDS ~62.5 KB,
// VGPR<=128 via launch_bounds). Wave = (h = wave>>2 in {0,1}: 16-b half, e = wave&3).
// Phase 1: D_e[r][b] over K=1024; 3 LDS bufs, 2-deep prefetch, 1 barrier/iter;
// per-wave uniform DMA count (waves 0-1: 2 Av + 1 Bx; waves 2-7: 2 Av) -> counted
// vmcnt(3)/(2). Gate logits = 1 extra MFMA on waves 0-1. tanh -> Tt -> C-mix ->
// w=g*tanh(.) -> wlds (16B-chunk XOR swizzle) -- w never touches HBM.
// Phase 2 (barrier-free): wave owns 64 d x 2 passes, A-frags direct from global U
// (L2-hot), B from wlds; epilogue via wave-private smf transpose -> 16 contiguous d
// per lane -> fully coalesced x0/xl reads + out/xb writes.
__global__ __launch_bounds__(512, 4) void layer_fused(const us* __restrict__ xs,
                                                      const us* __restrict__ Vt,
                                                      const us* __restrict__ Ce,
                                                      const us* __restrict__ gwb,
                                                      const us* __restrict__ x0b,
                                                      const us* __restrict__ Ub,
                                                      us* __restrict__ xbo,
                                                      const float* __restrict__ biasl,
                                                      float* __restrict__ out, int last) {
    const int row0 = blockIdx.x * 32;
    const int tid = threadIdx.x;
    const int lane = tid & 63, wave = tid >> 6;
    const int l15 = lane & 15, quad = lane >> 4;
    const int e = wave & 3, h = wave >> 2;
    const int e64 = e * 64;

    __shared__ __align__(16) union {
        struct { us buf[3][9216]; us gw[4096]; float gates[128]; } s;   // 62.5 KB
        us Tt[4][32 * LDM];                                             // 18 KB
        struct { us wlds[32 * 256]; float smf[8][1024]; } p2;           // 16 + 32 KB
    } u;

    const int kcA  = (lane & 3) ^ ((lane >> 3) & 3);   // source k-chunk for my slot
    const int sA   = quad ^ ((l15 >> 1) & 3);          // read slot
    const int rsub = lane >> 2;                        // 0..15

    // gw once: granule = kc*4 + gw_row; wave covers kc = wave*16 + rsub, row = lane&3
    ld_lds16(gwb + (size_t)(lane & 3) * DD + (wave * 16 + rsub) * 8, &u.s.gw[wave * 512]);

    auto STAGE = [&](int bi, int k0) {
        us* bb = u.s.buf[bi];
        #pragma unroll
        for (int j = 0; j < 2; ++j) {                  // Av rows wave*32 + j*16 + rsub
            int row = wave * 32 + j * 16 + rsub;
            ld_lds16(Vt + (size_t)row * DD + k0 + kcA * 8, &bb[(wave * 32 + j * 16) * 32]);
        }
        if (wave < 2) {                                // Bx rows wave*16 + rsub (32 b total)
            int row = wave * 16 + rsub;
            ld_lds16(xs + (size_t)(row0 + row) * DD + k0 + kcA * 8, &bb[8192 + wave * 512]);
        }
    };

    f32x4 acc[4] = {};
    f32x4 accg = {};
    STAGE(0, 0); STAGE(1, 32);

    int cur = 0;
    for (int t = 0; t < 32; ++t) {
        if (t < 31) {                                  // tile t done; tile t+1 may fly
            if (wave < 2) asm volatile("s_waitcnt vmcnt(3)" ::: "memory");
            else          asm volatile("s_waitcnt vmcnt(2)" ::: "memory");
        } else {
            asm volatile("s_waitcnt vmcnt(0)" ::: "memory");
        }
        __builtin_amdgcn_s_barrier();                  // tile t ready everywhere
        if (t < 30) {                                  // overwrites buf of tile t-1: safe
            int st = cur + 2; if (st >= 3) st -= 3;
            STAGE(st, (t + 2) * 32);
        }
        __builtin_amdgcn_sched_barrier(0);
        const us* bb = u.s.buf[cur];
        bf16x8 af[4], bfr;
        #pragma unroll
        for (int mt = 0; mt < 4; ++mt)
            af[mt] = *(const bf16x8*)&bb[(e64 + mt * 16 + l15) * 32 + sA * 8];
        bfr = *(const bf16x8*)&bb[8192 + (h * 16 + l15) * 32 + sA * 8];
        #pragma unroll
        for (int mt = 0; mt < 4; ++mt)
            acc[mt] = __builtin_amdgcn_mfma_f32_16x16x32_bf16(af[mt], bfr, acc[mt], 0, 0, 0);
        if (wave < 2) {   // gate logits (b = wave*16+l15; rows 0-3 = experts)
            bf16x8 bfrg = *(const bf16x8*)&bb[8192 + (wave * 16 + l15) * 32 + sA * 8];
            bf16x8 afg  = *(const bf16x8*)&u.s.gw[(t * 4 + quad) * 32 + (l15 & 3) * 8];
            accg = __builtin_amdgcn_mfma_f32_16x16x32_bf16(afg, bfrg, accg, 0, 0, 0);
        }
        cur = (cur + 1 == 3) ? 0 : cur + 1;
    }
    __builtin_amdgcn_s_barrier();                      // all buf reads done before Tt alias writes
    __builtin_amdgcn_sched_barrier(0);

    // tanh -> Tt_e[b][r] bf16 (wave writes its own (e,h) region)
    {
        us* Tt = u.Tt[e];
        #pragma unroll
        for (int mt = 0; mt < 4; ++mt) {
            int b = h * 16 + l15;
            us o[4];
            #pragma unroll
            for (int i = 0; i < 4; ++i) o[i] = f2b(fast_tanh(acc[mt][i]));
            *(ushort4*)&Tt[b * LDM + mt * 16 + quad * 4] = *(ushort4*)o;
        }
    }
    if (wave < 2 && quad == 0) {   // accg rows 0-3 = logits e0..e3 for b = wave*16+l15
        float l0 = accg[0], l1 = accg[1], l2 = accg[2], l3 = accg[3];
        float m = fmaxf(fmaxf(l0, l1), fmaxf(l2, l3));
        float g0 = __expf(l0 - m), g1 = __expf(l1 - m);
        float g2 = __expf(l2 - m), g3 = __expf(l3 - m);
        float inv = 1.f / (g0 + g1 + g2 + g3);
        int b = wave * 16 + l15;
        u.s.gates[0 * 32 + b] = g0 * inv; u.s.gates[1 * 32 + b] = g1 * inv;
        u.s.gates[2 * 32 + b] = g2 * inv; u.s.gates[3 * 32 + b] = g3 * inv;
    }
    __syncthreads();

    // t2 = tanh(C_e @ t1); C-frags direct from global bf16 (L2-hot)
    const us* Cb = Ce + (size_t)e * RR * RR;
    f32x4 acc2[4] = {};
    #pragma unroll
    for (int ks = 0; ks < 2; ++ks) {
        bf16x8 af2[4], bf2;
        #pragma unroll
        for (int mt = 0; mt < 4; ++mt)
            af2[mt] = *(const bf16x8*)&Cb[(size_t)(mt * 16 + l15) * RR + ks * 32 + quad * 8];
        bf2 = *(const bf16x8*)&u.Tt[e][(h * 16 + l15) * LDM + ks * 32 + quad * 8];
        #pragma unroll
        for (int mt = 0; mt < 4; ++mt)
            acc2[mt] = __builtin_amdgcn_mfma_f32_16x16x32_bf16(af2[mt], bf2, acc2[mt], 0, 0, 0);
    }
    __syncthreads();               // ALL Tt reads done before wlds (aliases Tt) writes

    // w = g * tanh(acc2) -> wlds[b][col] with 16B-chunk XOR swizzle: cc' = cc ^ (b&7)
    #pragma unroll
    for (int mt = 0; mt < 4; ++mt) {
        int b = h * 16 + l15;
        float g = u.s.gates[e * 32 + b];       // gates @63.5KB: disjoint from wlds
        us o[4];
        #pragma unroll
        for (int i = 0; i < 4; ++i) o[i] = f2b(g * fast_tanh(acc2[mt][i]));
        int col = e64 + mt * 16 + quad * 4;
        int cc = col >> 3, off = col & 7;
        *(ushort4*)&u.p2.wlds[b * 256 + ((cc ^ (b & 7)) << 3) + off] = *(ushort4*)o;
    }
    __syncthreads();               // wlds ready; phase 2 is barrier-free

    // ---- phase 2: D[d][b] = U . w^T; wave owns 64 d per pass, all 32 b ----
    const int bl = lane >> 2, dc3 = lane & 3;
    #pragma unroll 1
    for (int p = 0; p < 2; ++p) {
        const int dw = p * 512 + wave * 64;
        f32x4 pac[4][2] = {};
        #pragma unroll
        for (int s = 0; s < 8; ++s) {
            int e2 = s >> 1, r0 = (s & 1) * 32;
            bf16x8 af[4], bfr[2];
            #pragma unroll
            for (int mt = 0; mt < 4; ++mt) {
                int d = dw + mt * 16 + l15;
                af[mt] = *(const bf16x8*)&Ub[((size_t)e2 * DD + d) * RR + r0 + quad * 8];
            }
            #pragma unroll
            for (int nt = 0; nt < 2; ++nt) {
                int b = nt * 16 + l15;
                int cc = e2 * 8 + (r0 >> 3) + quad;
                bfr[nt] = *(const bf16x8*)&u.p2.wlds[b * 256 + ((cc ^ (b & 7)) << 3)];
            }
            #pragma unroll
            for (int mt = 0; mt < 4; ++mt)
                #pragma unroll
                for (int nt = 0; nt < 2; ++nt)
                    pac[mt][nt] = __builtin_amdgcn_mfma_f32_16x16x32_bf16(af[mt], bfr[nt], pac[mt][nt], 0, 0, 0);
        }
        // epilogue: bias for my 16 d, then per-nt transpose + combine
        const int dg = dw + dc3 * 16;
        float bfv[16];
        *(float4*)&bfv[0]  = *(const float4*)&biasl[dg];
        *(float4*)&bfv[4]  = *(const float4*)&biasl[dg + 4];
        *(float4*)&bfv[8]  = *(const float4*)&biasl[dg + 8];
        *(float4*)&bfv[12] = *(const float4*)&biasl[dg + 12];
        float* smf = u.p2.smf[wave];   // wave-private 4 KB
        #pragma unroll
        for (int nt = 0; nt < 2; ++nt) {
            #pragma unroll
            for (int mt = 0; mt < 4; ++mt) {
                int ch = (mt * 4 + quad) ^ (l15 & 7);
                *(f32x4*)&smf[l15 * 64 + ch * 4] = pac[mt][nt];
            }
            asm volatile("s_waitcnt lgkmcnt(0)" ::: "memory");
            __builtin_amdgcn_sched_barrier(0);
            const int brow = row0 + nt * 16 + bl;
            const size_t gb = (size_t)brow * DD + dg;
            uint xu[8], lu[8];
            *(uint4*)&xu[0] = *(const uint4*)&x0b[gb];
            *(uint4*)&xu[4] = *(const uint4*)&x0b[gb + 8];
            *(uint4*)&lu[0] = *(const uint4*)&xs[gb];
            *(uint4*)&lu[4] = *(const uint4*)&xs[gb + 8];
            float o[16];
            #pragma unroll
            for (int j = 0; j < 4; ++j) {
                int ch = (dc3 * 4 + j) ^ (bl & 7);
                float4 a = *(const float4*)&smf[bl * 64 + ch * 4];
                #pragma unroll
                for (int i = 0; i < 4; ++i) {
                    int k = j * 4 + i;
                    float av = (i == 0) ? a.x : (i == 1) ? a.y : (i == 2) ? a.z : a.w;
                    uint uu = xu[k >> 1], ll = lu[k >> 1];
                    float xv = b2f((k & 1) ? (us)(uu >> 16) : (us)(uu & 0xffff));
                    float xl = b2f((k & 1) ? (us)(ll >> 16) : (us)(ll & 0xffff));
                    o[k] = xv * (av + bfv[k]) + xl;
                }
            }
            if (last) {
                *(float4*)&out[gb]      = *(float4*)&o[0];
                *(float4*)&out[gb + 4]  = *(float4*)&o[4];
                *(float4*)&out[gb + 8]  = *(float4*)&o[8];
                *(float4*)&out[gb + 12] = *(float4*)&o[12];
            } else {
                us ob[16];
                #pragma unroll
                for (int k = 0; k < 16; ++k) ob[k] = f2b(o[k]);
                *(uint4*)&xbo[gb]     = *(uint4*)&ob[0];
                *(uint4*)&xbo[gb + 8] = *(uint4*)&ob[8];
            }
            asm volatile("s_waitcnt lgkmcnt(0)" ::: "memory");   // smf reads done before next nt writes
            __builtin_amdgcn_sched_barrier(0);
        }
    }
}

extern "C" void kernel_launch(void* const* d_in, const int* in_sizes, int n_in,
                              void* d_out, int out_size, void* d_ws, size_t ws_size,
                              hipStream_t stream) {
    const float* inputs = (const float*)d_in[0];
    const float* U      = (const float*)d_in[1];
    const float* V      = (const float*)d_in[2];
    const float* C      = (const float*)d_in[3];
    const float* gw     = (const float*)d_in[4];
    const float* bias   = (const float*)d_in[5];
    float* out = (float*)d_out;

    // ws: xb0 33.55 | xb 33.55 | gwb 8KB | Vt 1.57 | Ub 1.57 | Cb 0.10  = ~70.3 MB
    us* xb0 = (us*)d_ws;                         // bf16(inputs), const across layers
    us* xb  = xb0 + (size_t)BB * DD;             // residual stream
    us* gwb = xb + (size_t)BB * DD;
    us* Vt  = gwb + (size_t)EE * DD;
    us* Ub  = Vt + (size_t)LL * EE * RR * DD;
    us* Cb  = Ub + (size_t)LL * EE * DD * RR;

    convF2B<<<dim3(BB * DD / 1024), 256, 0, stream>>>(inputs, xb0);
    convF2B<<<dim3(LL * EE * DD * RR / 1024), 256, 0, stream>>>(U, Ub);
    convF2B<<<dim3(LL * EE * RR * RR / 1024), 256, 0, stream>>>(C, Cb);
    convF2B<<<dim3(EE * DD / 1024), 256, 0, stream>>>(gw, gwb);
    convV<<<dim3(LL * EE, DD / 64), 256, 0, stream>>>(V, Vt);

    for (int i = 0; i < LL; ++i) {
        const us* xs = (i == 0) ? xb0 : xb;
        layer_fused<<<dim3(BB / 32), 512, 0, stream>>>(
            xs, Vt + (size_t)i * EE * RR * DD, Cb + (size_t)i * EE * RR * RR, gwb,
            xb0, Ub + (size_t)i * EE * DD * RR, xb, bias + (size_t)i * DD,
            out, i == LL - 1);
    }
}